// Round 2
// baseline (271.636 us; speedup 1.0000x reference)
//
#include <hip/hip_runtime.h>
#include <hip/hip_bf16.h>
#include <math.h>

#define H 1024
#define R 64
#define BM 32
#define NTHREADS 256
#define TSTRIDE 72   // padded t_lds row stride (elements) -> 144B, breaks bank conflicts

typedef __attribute__((ext_vector_type(8))) short short8;
typedef __attribute__((ext_vector_type(4))) float floatx4;

__device__ __forceinline__ unsigned short f2bf(float f) {
    unsigned int u = __builtin_bit_cast(unsigned int, f);
    u += 0x7fffu + ((u >> 16) & 1u);   // round-to-nearest-even
    return (unsigned short)(u >> 16);
}

// ---- prep: re-layout weights into bf16 MFMA B-fragments in ws ----
// frag layout: frag f, lane l, elem j  ->  ws[(f*64 + l)*8 + j]
// W_down (1024x64): f = kk*4 + n   (kk: k-step of 32, n: 16-col tile), elem = W[kk*32 + (l>>4)*8 + j][n*16 + (l&15)]
// W_up   (64x1024): f = ks*64 + n  (ks: k-step of 32, n: 16-col tile), elem = W[ks*32 + (l>>4)*8 + j][n*16 + (l&15)]
__global__ void prep_weights(const float* __restrict__ w_down,
                             const float* __restrict__ w_up,
                             unsigned short* __restrict__ wsd,
                             unsigned short* __restrict__ wsu) {
    int tid = blockIdx.x * blockDim.x + threadIdx.x;   // 0..65535
    int j    = tid & 7;
    int lane = (tid >> 3) & 63;
    int f    = tid >> 9;                               // 0..127
    int b = lane >> 4, p = lane & 15;
    {
        int kk = f >> 2, n = f & 3;
        int row = kk * 32 + b * 8 + j;
        int col = n * 16 + p;
        wsd[tid] = f2bf(w_down[row * R + col]);
    }
    {
        int ks = f >> 6, n = f & 63;
        int row = ks * 32 + b * 8 + j;
        int col = n * 16 + p;
        wsu[tid] = f2bf(w_up[row * H + col]);
    }
}

__global__ __launch_bounds__(NTHREADS, 2)
void adapter_kernel(const float* __restrict__ x,
                    const float* __restrict__ gamma,
                    const float* __restrict__ beta,
                    const float* __restrict__ b_down,
                    const float* __restrict__ b_up,
                    const unsigned short* __restrict__ wsd,
                    const unsigned short* __restrict__ wsu,
                    float* __restrict__ out) {
    // y_lds: LN'd rows, bf16, XOR-swizzled in 8-elem (16B) groups: slot = g ^ (row&7)
    __shared__ __align__(16) unsigned short y_lds[BM * H];
    __shared__ __align__(16) unsigned short t_lds[BM * TSTRIDE];

    const int tid  = threadIdx.x;
    const int lane = tid & 63;
    const int wave = tid >> 6;
    const long rowbase = (long)blockIdx.x * BM;

    // ---------------- phase 1: load + LayerNorm -> y_lds (bf16, swizzled) ----
    // gamma/beta cache for this lane's 16 columns (same for every row)
    float gg[16], bb[16];
    {
        const floatx4* g4 = (const floatx4*)(gamma + lane * 16);
        const floatx4* b4 = (const floatx4*)(beta  + lane * 16);
        #pragma unroll
        for (int q = 0; q < 4; ++q) {
            floatx4 gv = g4[q], bv = b4[q];
            #pragma unroll
            for (int e = 0; e < 4; ++e) { gg[q*4+e] = gv[e]; bb[q*4+e] = bv[e]; }
        }
    }
    #pragma unroll 2
    for (int i = 0; i < 8; ++i) {
        int r = wave * 8 + i;
        const floatx4* xr = (const floatx4*)(x + (rowbase + r) * H + lane * 16);
        float v[16];
        #pragma unroll
        for (int q = 0; q < 4; ++q) {
            floatx4 xv = xr[q];
            #pragma unroll
            for (int e = 0; e < 4; ++e) v[q*4+e] = xv[e];
        }
        float s1 = 0.f, s2 = 0.f;
        #pragma unroll
        for (int q = 0; q < 16; ++q) { s1 += v[q]; s2 += v[q] * v[q]; }
        #pragma unroll
        for (int off = 32; off >= 1; off >>= 1) {
            s1 += __shfl_xor(s1, off);
            s2 += __shfl_xor(s2, off);
        }
        float mu  = s1 * (1.0f / (float)H);
        float var = s2 * (1.0f / (float)H) - mu * mu;
        float rs  = rsqrtf(var + 1e-5f);
        int c = r & 7;
        short8 lo, hi;
        #pragma unroll
        for (int q = 0; q < 8; ++q) lo[q] = (short)f2bf((v[q]     - mu) * rs * gg[q]     + bb[q]);
        #pragma unroll
        for (int q = 0; q < 8; ++q) hi[q] = (short)f2bf((v[q + 8] - mu) * rs * gg[q + 8] + bb[q + 8]);
        int s0 = (2 * lane)     ^ c;
        int s1g = (2 * lane + 1) ^ c;
        *(short8*)&y_lds[r * H + s0  * 8] = lo;
        *(short8*)&y_lds[r * H + s1g * 8] = hi;
    }
    __syncthreads();

    // ---------------- phase 2: down-proj (32 rows x 64) + bias + GELU -> t_lds
    const int g = wave >> 1;       // row-group: rows 16g..16g+15
    const int c = wave & 1;        // col-half:  cols 32c..32c+31
    const int p = lane & 15;
    const int b = lane >> 4;

    floatx4 acc0 = {0.f, 0.f, 0.f, 0.f};
    floatx4 acc1 = {0.f, 0.f, 0.f, 0.f};
    const int arow = 16 * g + p;
    const int asw  = arow & 7;
    const short8* wsd8 = (const short8*)wsd;
    #pragma unroll 4
    for (int kk = 0; kk < 32; ++kk) {
        int gidx = 4 * kk + b;
        short8 a  = *(const short8*)&y_lds[arow * H + ((gidx ^ asw) * 8)];
        short8 b0 = wsd8[(kk * 4 + 2 * c)     * 64 + lane];
        short8 b1 = wsd8[(kk * 4 + 2 * c + 1) * 64 + lane];
        acc0 = __builtin_amdgcn_mfma_f32_16x16x32_bf16(a, b0, acc0, 0, 0, 0);
        acc1 = __builtin_amdgcn_mfma_f32_16x16x32_bf16(a, b1, acc1, 0, 0, 0);
    }
    {
        float bd0 = b_down[32 * c + p];
        float bd1 = b_down[32 * c + 16 + p];
        #pragma unroll
        for (int reg = 0; reg < 4; ++reg) {
            int trow = 16 * g + b * 4 + reg;
            float u0 = acc0[reg] + bd0;
            float u1 = acc1[reg] + bd1;
            u0 = 0.5f * u0 * (1.0f + erff(u0 * 0.70710678f));
            u1 = 0.5f * u1 * (1.0f + erff(u1 * 0.70710678f));
            t_lds[trow * TSTRIDE + 32 * c + p]      = f2bf(u0);
            t_lds[trow * TSTRIDE + 32 * c + 16 + p] = f2bf(u1);
        }
    }
    __syncthreads();

    // ---------------- phase 3: up-proj + b_up + residual -> out -------------
    const int arow3 = 16 * g + p;
    short8 a0 = *(const short8*)&t_lds[arow3 * TSTRIDE + b * 8];        // k = 0..31
    short8 a1 = *(const short8*)&t_lds[arow3 * TSTRIDE + 32 + b * 8];   // k = 32..63
    const short8* wsu8 = (const short8*)wsu;
    const long rb = rowbase + 16 * g;

    #pragma unroll 2
    for (int nn = 0; nn < 32; ++nn) {
        int n = 32 * c + nn;                 // global 16-col tile
        short8 bu0 = wsu8[(n)      * 64 + lane];
        short8 bu1 = wsu8[(64 + n) * 64 + lane];
        floatx4 acc = {0.f, 0.f, 0.f, 0.f};
        acc = __builtin_amdgcn_mfma_f32_16x16x32_bf16(a0, bu0, acc, 0, 0, 0);
        acc = __builtin_amdgcn_mfma_f32_16x16x32_bf16(a1, bu1, acc, 0, 0, 0);
        int col = n * 16 + p;
        float bup = b_up[col];
        #pragma unroll
        for (int reg = 0; reg < 4; ++reg) {
            long rr = rb + b * 4 + reg;
            out[rr * H + col] = acc[reg] + bup + x[rr * H + col];
        }
    }
}

extern "C" void kernel_launch(void* const* d_in, const int* in_sizes, int n_in,
                              void* d_out, int out_size, void* d_ws, size_t ws_size,
                              hipStream_t stream) {
    const float* x      = (const float*)d_in[0];
    const float* gamma  = (const float*)d_in[1];
    const float* beta   = (const float*)d_in[2];
    const float* w_down = (const float*)d_in[3];
    const float* b_down = (const float*)d_in[4];
    const float* w_up   = (const float*)d_in[5];
    const float* b_up   = (const float*)d_in[6];
    float* out = (float*)d_out;

    unsigned short* wsd = (unsigned short*)d_ws;
    unsigned short* wsu = wsd + 65536;

    int M = in_sizes[0] / H;                 // 32768 rows
    prep_weights<<<256, 256, 0, stream>>>(w_down, w_up, wsd, wsu);
    adapter_kernel<<<M / BM, NTHREADS, 0, stream>>>(x, gamma, beta, b_down, b_up,
                                                    wsd, wsu, out);
}

// Round 4
// 268.693 us; speedup vs baseline: 1.0110x; 1.0110x over previous
//
#include <hip/hip_runtime.h>
#include <hip/hip_bf16.h>
#include <math.h>

#define H 1024
#define R 64
#define BM 16        // rows per block (16 -> 35KB LDS -> 4 blocks/CU vs 2 at BM=32)
#define NTHREADS 256
#define TSTRIDE 72   // padded t_lds row stride (elements) -> 144B, breaks bank conflicts

typedef __attribute__((ext_vector_type(8))) short short8;
typedef __attribute__((ext_vector_type(4))) float floatx4;

__device__ __forceinline__ unsigned short f2bf(float f) {
    unsigned int u = __builtin_bit_cast(unsigned int, f);
    u += 0x7fffu + ((u >> 16) & 1u);   // round-to-nearest-even
    return (unsigned short)(u >> 16);
}

// ---- prep: re-layout weights into bf16 MFMA B-fragments in ws ----
// frag layout: frag f, lane l, elem j  ->  ws[(f*64 + l)*8 + j]
// W_down (1024x64): f = kk*4 + n   (kk: k-step of 32, n: 16-col tile), elem = W[kk*32 + (l>>4)*8 + j][n*16 + (l&15)]
// W_up   (64x1024): f = ks*64 + n  (ks: k-step of 32, n: 16-col tile), elem = W[ks*32 + (l>>4)*8 + j][n*16 + (l&15)]
__global__ void prep_weights(const float* __restrict__ w_down,
                             const float* __restrict__ w_up,
                             unsigned short* __restrict__ wsd,
                             unsigned short* __restrict__ wsu) {
    int tid = blockIdx.x * blockDim.x + threadIdx.x;   // 0..65535
    int j    = tid & 7;
    int lane = (tid >> 3) & 63;
    int f    = tid >> 9;                               // 0..127
    int b = lane >> 4, p = lane & 15;
    {
        int kk = f >> 2, n = f & 3;
        int row = kk * 32 + b * 8 + j;
        int col = n * 16 + p;
        wsd[tid] = f2bf(w_down[row * R + col]);
    }
    {
        int ks = f >> 6, n = f & 63;
        int row = ks * 32 + b * 8 + j;
        int col = n * 16 + p;
        wsu[tid] = f2bf(w_up[row * H + col]);
    }
}

__global__ __launch_bounds__(NTHREADS, 4)
void adapter_kernel(const float* __restrict__ x,
                    const float* __restrict__ gamma,
                    const float* __restrict__ beta,
                    const float* __restrict__ b_down,
                    const float* __restrict__ b_up,
                    const unsigned short* __restrict__ wsd,
                    const unsigned short* __restrict__ wsu,
                    float* __restrict__ out) {
    // y_lds: LN'd rows, bf16, XOR-swizzled in 8-elem (16B) groups: slot = g ^ (row&7)
    __shared__ __align__(16) unsigned short y_lds[BM * H];      // 32 KB
    __shared__ __align__(16) unsigned short t_lds[BM * TSTRIDE];

    const int tid  = threadIdx.x;
    const int lane = tid & 63;
    const int wave = tid >> 6;
    const long rowbase = (long)blockIdx.x * BM;

    // ---------------- phase 1: load + LayerNorm -> y_lds (bf16, swizzled) ----
    float gg[16], bb[16];
    {
        const floatx4* g4 = (const floatx4*)(gamma + lane * 16);
        const floatx4* b4 = (const floatx4*)(beta  + lane * 16);
        #pragma unroll
        for (int q = 0; q < 4; ++q) {
            floatx4 gv = g4[q], bv = b4[q];
            #pragma unroll
            for (int e = 0; e < 4; ++e) { gg[q*4+e] = gv[e]; bb[q*4+e] = bv[e]; }
        }
    }
    #pragma unroll 2
    for (int i = 0; i < 4; ++i) {
        int r = wave * 4 + i;                       // 4 rows per wave, 16 total
        const floatx4* xr = (const floatx4*)(x + (rowbase + r) * H + lane * 16);
        float v[16];
        #pragma unroll
        for (int q = 0; q < 4; ++q) {
            floatx4 xv = xr[q];
            #pragma unroll
            for (int e = 0; e < 4; ++e) v[q*4+e] = xv[e];
        }
        float s1 = 0.f, s2 = 0.f;
        #pragma unroll
        for (int q = 0; q < 16; ++q) { s1 += v[q]; s2 += v[q] * v[q]; }
        #pragma unroll
        for (int off = 32; off >= 1; off >>= 1) {
            s1 += __shfl_xor(s1, off);
            s2 += __shfl_xor(s2, off);
        }
        float mu  = s1 * (1.0f / (float)H);
        float var = s2 * (1.0f / (float)H) - mu * mu;
        float rs  = rsqrtf(var + 1e-5f);
        int c = r & 7;
        short8 lo, hi;
        #pragma unroll
        for (int q = 0; q < 8; ++q) lo[q] = (short)f2bf((v[q]     - mu) * rs * gg[q]     + bb[q]);
        #pragma unroll
        for (int q = 0; q < 8; ++q) hi[q] = (short)f2bf((v[q + 8] - mu) * rs * gg[q + 8] + bb[q + 8]);
        int s0  = (2 * lane)     ^ c;
        int s1g = (2 * lane + 1) ^ c;
        *(short8*)&y_lds[r * H + s0  * 8] = lo;
        *(short8*)&y_lds[r * H + s1g * 8] = hi;
    }
    __syncthreads();

    // ---------------- phase 2: down-proj (16 rows x 16 cols per wave) + GELU
    const int p = lane & 15;
    const int b = lane >> 4;

    floatx4 acc = {0.f, 0.f, 0.f, 0.f};
    const int asw = p & 7;
    const short8* wsd8 = (const short8*)wsd;
    #pragma unroll 4
    for (int kk = 0; kk < 32; ++kk) {
        int gidx = 4 * kk + b;
        short8 a  = *(const short8*)&y_lds[p * H + ((gidx ^ asw) * 8)];
        short8 b0 = wsd8[(kk * 4 + wave) * 64 + lane];    // col-tile = wave
        acc = __builtin_amdgcn_mfma_f32_16x16x32_bf16(a, b0, acc, 0, 0, 0);
    }
    {
        float bd = b_down[16 * wave + p];
        #pragma unroll
        for (int reg = 0; reg < 4; ++reg) {
            int trow = b * 4 + reg;
            float u = acc[reg] + bd;
            u = 0.5f * u * (1.0f + erff(u * 0.70710678f));
            t_lds[trow * TSTRIDE + 16 * wave + p] = f2bf(u);
        }
    }
    __syncthreads();

    // ---------------- phase 3: up-proj + b_up + residual -> out -------------
    short8 a0 = *(const short8*)&t_lds[p * TSTRIDE + b * 8];        // k = 0..31
    short8 a1 = *(const short8*)&t_lds[p * TSTRIDE + 32 + b * 8];   // k = 32..63
    const short8* wsu8 = (const short8*)wsu;

    #pragma unroll 2
    for (int nn = 0; nn < 16; ++nn) {
        int n = 16 * wave + nn;              // global 16-col tile (wave owns 16 tiles)
        short8 bu0 = wsu8[(n)      * 64 + lane];
        short8 bu1 = wsu8[(64 + n) * 64 + lane];
        floatx4 av = {0.f, 0.f, 0.f, 0.f};
        av = __builtin_amdgcn_mfma_f32_16x16x32_bf16(a0, bu0, av, 0, 0, 0);
        av = __builtin_amdgcn_mfma_f32_16x16x32_bf16(a1, bu1, av, 0, 0, 0);
        int col = n * 16 + p;
        float bup = b_up[col];
        #pragma unroll
        for (int reg = 0; reg < 4; ++reg) {
            long rr = rowbase + b * 4 + reg;
            out[rr * H + col] = av[reg] + bup + x[rr * H + col];
        }
    }
}

extern "C" void kernel_launch(void* const* d_in, const int* in_sizes, int n_in,
                              void* d_out, int out_size, void* d_ws, size_t ws_size,
                              hipStream_t stream) {
    const float* x      = (const float*)d_in[0];
    const float* gamma  = (const float*)d_in[1];
    const float* beta   = (const float*)d_in[2];
    const float* w_down = (const float*)d_in[3];
    const float* b_down = (const float*)d_in[4];
    const float* w_up   = (const float*)d_in[5];
    const float* b_up   = (const float*)d_in[6];
    float* out = (float*)d_out;

    unsigned short* wsd = (unsigned short*)d_ws;
    unsigned short* wsu = wsd + 65536;

    int M = in_sizes[0] / H;                 // 32768 rows
    prep_weights<<<256, 256, 0, stream>>>(w_down, w_up, wsd, wsu);
    adapter_kernel<<<M / BM, NTHREADS, 0, stream>>>(x, gamma, beta, b_down, b_up,
                                                    wsd, wsu, out);
}